// Round 1
// baseline (11501.099 us; speedup 1.0000x reference)
//
#include <hip/hip_runtime.h>

#define ENCD 2048
#define ATTD 512
#define HIDD 512
#define NB 64
#define NP 196
#define NT 20
#define NV 32000
#define NE 512

// ---------------- mean over P: meT[k*64+b] = mean_p enc[b,p,k] ----------------
__global__ void mean_kernel(const float* __restrict__ enc, float* __restrict__ meT) {
  int b = blockIdx.x >> 3, kq = blockIdx.x & 7;
  int k = kq * 256 + threadIdx.x;
  const float* base = enc + (size_t)b * NP * ENCD + k;
  float acc = 0.f;
  for (int p = 0; p < NP; ++p) acc += base[(size_t)p * ENCD];
  meT[k * NB + b] = acc * (1.f / NP);
}

// ---------------- embedding gather, transposed: embT[t][k][b] ----------------
__global__ void emb_kernel(const int* __restrict__ captions, const float* __restrict__ emb,
                           float* __restrict__ embT) {
  int t = blockIdx.x >> 1, half = blockIdx.x & 1;
  for (int i = 0; i < 64; ++i) {
    int idx = half * 16384 + i * 256 + threadIdx.x;   // idx = k*64 + b
    int k = idx >> 6, b = idx & 63;
    int cap = captions[b * NT + t];
    embT[(size_t)t * (NE * NB) + idx] = emb[(size_t)cap * NE + k];
  }
}

// ---------------- att1 = enc(12544x2048) @ Wea(2048x512) + bea ----------------
__global__ void gemm_att1(const float* __restrict__ A, const float* __restrict__ Bw,
                          const float* __restrict__ bea, float* __restrict__ C) {
  __shared__ float As[16][64];   // [k][m]
  __shared__ float Bs[16][64];   // [k][n]
  int tid = threadIdx.x;
  int tx = tid & 15, ty = tid >> 4;
  int m0 = blockIdx.x * 64, n0 = blockIdx.y * 64;
  float acc[4][4] = {};
  for (int k0 = 0; k0 < ENCD; k0 += 16) {
    __syncthreads();
    {
      int m = tid >> 2, kq = tid & 3;
      const float4 a4 = *(const float4*)&A[(size_t)(m0 + m) * ENCD + k0 + kq * 4];
      As[kq * 4 + 0][m] = a4.x; As[kq * 4 + 1][m] = a4.y;
      As[kq * 4 + 2][m] = a4.z; As[kq * 4 + 3][m] = a4.w;
      for (int i = 0; i < 4; ++i) {
        int e = tid + i * 256; int k = e >> 6, n = e & 63;
        Bs[k][n] = Bw[(size_t)(k0 + k) * ATTD + n0 + n];
      }
    }
    __syncthreads();
#pragma unroll
    for (int kk = 0; kk < 16; ++kk) {
      float4 av = *(const float4*)&As[kk][ty * 4];
      float4 bv = *(const float4*)&Bs[kk][tx * 4];
      float a[4] = {av.x, av.y, av.z, av.w};
      float b[4] = {bv.x, bv.y, bv.z, bv.w};
#pragma unroll
      for (int i = 0; i < 4; ++i)
#pragma unroll
        for (int j = 0; j < 4; ++j) acc[i][j] += a[i] * b[j];
    }
  }
  for (int i = 0; i < 4; ++i)
    for (int j = 0; j < 4; ++j) {
      int m = m0 + ty * 4 + i, n = n0 + tx * 4 + j;
      C[(size_t)m * ATTD + n] = acc[i][j] + bea[n];
    }
}

// ------- generic: out[j] (all 64 b) = sum_k xT[k*64+b] * W[j*sj + k*sk] + bias[j]
// writes transposed outT[j*64+b] (and optional copy outT2), and/or normal outN[b*J+j]
__global__ void gemmT_kernel(const float* __restrict__ xT, int K,
                             const float* __restrict__ W, int sj, int sk,
                             const float* __restrict__ bias,
                             float* __restrict__ outT, float* __restrict__ outT2,
                             float* __restrict__ outN, int J) {
  __shared__ float xs[4096];
  int tid = threadIdx.x, lane = tid & 63, wid = tid >> 6;
  int j0 = __builtin_amdgcn_readfirstlane(blockIdx.x * 8 + wid * 2);
  const float* w0 = W + (size_t)j0 * sj;
  const float* w1 = W + (size_t)(j0 + 1) * sj;
  float acc0 = 0.f, acc1 = 0.f;
  for (int k0 = 0; k0 < K; k0 += 64) {
    __syncthreads();
    for (int i = 0; i < 16; ++i) xs[i * 256 + tid] = xT[k0 * 64 + i * 256 + tid];
    __syncthreads();
#pragma unroll 8
    for (int kk = 0; kk < 64; ++kk) {
      float xv = xs[kk * 64 + lane];
      int c = (k0 + kk) * sk;
      acc0 += xv * w0[c];
      acc1 += xv * w1[c];
    }
  }
  float o0 = acc0 + (bias ? bias[j0] : 0.f);
  float o1 = acc1 + (bias ? bias[j0 + 1] : 0.f);
  if (outT) { outT[j0 * 64 + lane] = o0; outT[(j0 + 1) * 64 + lane] = o1; }
  if (outT2) { outT2[j0 * 64 + lane] = o0; outT2[(j0 + 1) * 64 + lane] = o1; }
  if (outN) { outN[lane * J + j0] = o0; outN[lane * J + j0 + 1] = o1; }
}

// ---------------- e[b,p] = relu(att1[b,p,:]+att2[b,:]) . Wfa + bfa ----------------
__global__ void escore_kernel(const float* __restrict__ att1, const float* __restrict__ att2,
                              const float* __restrict__ Wfa, const float* __restrict__ bfa,
                              float* __restrict__ e) {
  int wid = threadIdx.x >> 6, lane = threadIdx.x & 63;
  int idx = blockIdx.x * 4 + wid;          // = b*196 + p
  int b = idx / NP;
  const float* arow = att1 + (size_t)idx * ATTD;
  const float* a2 = att2 + (size_t)b * ATTD;
  float acc = 0.f;
#pragma unroll
  for (int i = 0; i < 8; ++i) {
    int a = lane + i * 64;
    float v = arow[a] + a2[a];
    v = fmaxf(v, 0.f);
    acc += v * Wfa[a];
  }
  for (int off = 32; off; off >>= 1) acc += __shfl_xor(acc, off, 64);
  if (lane == 0) e[idx] = acc + bfa[0];
}

// ---------------- softmax over P then aweT[d*64+b] = sum_p alpha*enc ----------------
__global__ void smax_awe_kernel(const float* __restrict__ e, const float* __restrict__ enc,
                                float* __restrict__ aweT) {
  int b = blockIdx.x >> 3, dq = blockIdx.x & 7;
  int tid = threadIdx.x;
  __shared__ float sm[256];
  __shared__ float alpha[NP];
  float v = (tid < NP) ? e[b * NP + tid] : -1e30f;
  sm[tid] = v; __syncthreads();
  for (int s = 128; s; s >>= 1) { if (tid < s) sm[tid] = fmaxf(sm[tid], sm[tid + s]); __syncthreads(); }
  float m = sm[0]; __syncthreads();
  float ex = (tid < NP) ? expf(v - m) : 0.f;
  sm[tid] = ex; __syncthreads();
  for (int s = 128; s; s >>= 1) { if (tid < s) sm[tid] += sm[tid + s]; __syncthreads(); }
  float ssum = sm[0]; __syncthreads();
  if (tid < NP) alpha[tid] = ex / ssum;
  __syncthreads();
  int d = dq * 256 + tid;
  const float* base = enc + (size_t)b * NP * ENCD + d;
  float acc = 0.f;
  for (int p = 0; p < NP; ++p) acc += alpha[p] * base[(size_t)p * ENCD];
  aweT[d * NB + b] = acc;
}

// ---------------- fused LSTM gates + cell (wave per j0 in [0,512)) ----------------
__global__ void lstm_fused(const float* __restrict__ xT1, int K1,
                           const float* __restrict__ xT2, int K2,
                           const float* __restrict__ hT,
                           const float* __restrict__ W_ih, int ld_ih,
                           const float* __restrict__ W_hh,
                           const float* __restrict__ b_ih, const float* __restrict__ b_hh,
                           const float* __restrict__ cT_in,
                           float* __restrict__ hT_out, float* __restrict__ cT_out) {
  __shared__ float xs[4096];
  int tid = threadIdx.x, lane = tid & 63, wid = tid >> 6;
  int j0 = __builtin_amdgcn_readfirstlane(blockIdx.x * 4 + wid);   // [0,512)
  float ai = 0.f, af = 0.f, ag = 0.f, ao = 0.f;

  auto seg = [&](const float* __restrict__ src, int Ks, const float* __restrict__ Wb,
                 int ld, int c0) {
    const float* ri = Wb + (size_t)j0 * ld + c0;
    const float* rf = Wb + (size_t)(j0 + 512) * ld + c0;
    const float* rg = Wb + (size_t)(j0 + 1024) * ld + c0;
    const float* ro = Wb + (size_t)(j0 + 1536) * ld + c0;
    for (int k0 = 0; k0 < Ks; k0 += 64) {
      __syncthreads();
      for (int i = 0; i < 16; ++i) xs[i * 256 + tid] = src[k0 * 64 + i * 256 + tid];
      __syncthreads();
#pragma unroll 8
      for (int kk = 0; kk < 64; ++kk) {
        float xv = xs[kk * 64 + lane];
        int c = k0 + kk;
        ai += xv * ri[c]; af += xv * rf[c]; ag += xv * rg[c]; ao += xv * ro[c];
      }
    }
  };

  seg(xT1, K1, W_ih, ld_ih, 0);
  if (xT2) seg(xT2, K2, W_ih, ld_ih, K1);
  seg(hT, HIDD, W_hh, HIDD, 0);

  ai += b_ih[j0] + b_hh[j0];
  af += b_ih[j0 + 512] + b_hh[j0 + 512];
  ag += b_ih[j0 + 1024] + b_hh[j0 + 1024];
  ao += b_ih[j0 + 1536] + b_hh[j0 + 1536];
  float c_old = cT_in[j0 * 64 + lane];
  float si = 1.f / (1.f + expf(-ai));
  float sf = 1.f / (1.f + expf(-af));
  float so = 1.f / (1.f + expf(-ao));
  float cn = sf * c_old + si * tanhf(ag);
  float hn = so * tanhf(cn);
  hT_out[j0 * 64 + lane] = hn;
  cT_out[j0 * 64 + lane] = cn;
}

// ---------------- pred[b, t, v] = h1 . Wfc[:,v] + bfc[v] ----------------
// wave: 64 v's on lanes, 32 b's in acc (h1 via scalar loads)
__global__ void pred_kernel(const float* __restrict__ h1T, const float* __restrict__ Wfc,
                            const float* __restrict__ bfc, float* __restrict__ out, int t) {
  int tid = threadIdx.x, lane = tid & 63, wid = tid >> 6;
  int gw = blockIdx.x * 4 + wid;          // 0..999
  int vt = gw % 500, bh = gw / 500;       // 500 v-tiles x 2 b-halves
  int v = vt * 64 + lane;
  int b0 = __builtin_amdgcn_readfirstlane(bh * 32);
  float acc[32] = {};
  for (int h = 0; h < HIDD; ++h) {
    float w = Wfc[(size_t)h * NV + v];
    const float* hrow = h1T + h * 64 + b0;
#pragma unroll
    for (int i = 0; i < 32; ++i) acc[i] += hrow[i] * w;
  }
  float bv = bfc[v];
#pragma unroll
  for (int i = 0; i < 32; ++i)
    out[((size_t)(b0 + i) * NT + t) * NV + v] = acc[i] + bv;
}

extern "C" void kernel_launch(void* const* d_in, const int* in_sizes, int n_in,
                              void* d_out, int out_size, void* d_ws, size_t ws_size,
                              hipStream_t stream) {
  const float* enc   = (const float*)d_in[0];
  const int*   caps  = (const int*)d_in[1];
  const float* emb   = (const float*)d_in[3];
  const float* Wea   = (const float*)d_in[4];
  const float* bea   = (const float*)d_in[5];
  const float* Wda   = (const float*)d_in[6];
  const float* bda   = (const float*)d_in[7];
  const float* Wfa   = (const float*)d_in[8];
  const float* bfa   = (const float*)d_in[9];
  const float* W_ih0 = (const float*)d_in[10];
  const float* W_hh0 = (const float*)d_in[11];
  const float* b_ih0 = (const float*)d_in[12];
  const float* b_hh0 = (const float*)d_in[13];
  const float* W_ih1 = (const float*)d_in[14];
  const float* W_hh1 = (const float*)d_in[15];
  const float* b_ih1 = (const float*)d_in[16];
  const float* b_hh1 = (const float*)d_in[17];
  const float* Wfc   = (const float*)d_in[18];
  const float* bfc   = (const float*)d_in[19];
  const float* Wih   = (const float*)d_in[20];
  const float* bih   = (const float*)d_in[21];
  const float* Wic   = (const float*)d_in[22];
  const float* bic   = (const float*)d_in[23];
  float* out = (float*)d_out;

  float* w = (float*)d_ws;
  float* att1 = w;  w += (size_t)NB * NP * ATTD;   // 6,422,528
  float* meT  = w;  w += ENCD * NB;                // 131,072
  float* embT = w;  w += NT * NE * NB;             // 655,360
  float* aweT = w;  w += ENCD * NB;                // 131,072
  float* att2 = w;  w += NB * ATTD;                // 32,768
  float* ebuf = w;  w += NB * NP;                  // 12,544
  float* h0T[2] = { w, w + 32768 };  w += 65536;
  float* c0T[2] = { w, w + 32768 };  w += 65536;
  float* h1T[2] = { w, w + 32768 };  w += 65536;
  float* c1T[2] = { w, w + 32768 };  w += 65536;

  // ---- precompute ----
  mean_kernel<<<512, 256, 0, stream>>>(enc, meT);
  emb_kernel<<<NT * 2, 256, 0, stream>>>(caps, emb, embT);
  gemm_att1<<<dim3(NP * NB / 64, ATTD / 64), 256, 0, stream>>>(enc, Wea, bea, att1);
  // h0 = meanenc @ Wih + bih (copied to both layers); same for c
  gemmT_kernel<<<64, 256, 0, stream>>>(meT, ENCD, Wih, 1, HIDD, bih, h0T[0], h1T[0], nullptr, 0);
  gemmT_kernel<<<64, 256, 0, stream>>>(meT, ENCD, Wic, 1, HIDD, bic, c0T[0], c1T[0], nullptr, 0);

  int cur = 0;
  for (int t = 0; t < NT; ++t) {
    int nxt = cur ^ 1;
    // att2 = h1 @ Wda + bda  (normal layout [b][a])
    gemmT_kernel<<<64, 256, 0, stream>>>(h1T[cur], HIDD, Wda, 1, ATTD, bda,
                                         nullptr, nullptr, att2, ATTD);
    escore_kernel<<<NB * NP / 4, 256, 0, stream>>>(att1, att2, Wfa, bfa, ebuf);
    smax_awe_kernel<<<512, 256, 0, stream>>>(ebuf, enc, aweT);
    lstm_fused<<<128, 256, 0, stream>>>(embT + (size_t)t * NE * NB, NE, aweT, ENCD,
                                        h0T[cur], W_ih0, NE + ENCD, W_hh0,
                                        b_ih0, b_hh0, c0T[cur], h0T[nxt], c0T[nxt]);
    lstm_fused<<<128, 256, 0, stream>>>(h0T[nxt], HIDD, nullptr, 0,
                                        h1T[cur], W_ih1, HIDD, W_hh1,
                                        b_ih1, b_hh1, c1T[cur], h1T[nxt], c1T[nxt]);
    pred_kernel<<<250, 256, 0, stream>>>(h1T[nxt], Wfc, bfc, out, t);
    cur = nxt;
  }
}

// Round 2
// 10255.080 us; speedup vs baseline: 1.1215x; 1.1215x over previous
//
#include <hip/hip_runtime.h>

#define ENCD 2048
#define ATTD 512
#define HIDD 512
#define NB 64
#define NP 196
#define NT 20
#define NV 32000
#define NE 512

// ---------------- mean over P: meT[k*64+b] = mean_p enc[b,p,k] ----------------
__global__ void mean_kernel(const float* __restrict__ enc, float* __restrict__ meT) {
  int b = blockIdx.x >> 3, kq = blockIdx.x & 7;
  int k = kq * 256 + threadIdx.x;
  const float* base = enc + (size_t)b * NP * ENCD + k;
  float acc = 0.f;
  for (int p = 0; p < NP; ++p) acc += base[(size_t)p * ENCD];
  meT[k * NB + b] = acc * (1.f / NP);
}

// ---------------- embedding gather, transposed: embT[t][k][b] ----------------
__global__ void emb_kernel(const int* __restrict__ captions, const float* __restrict__ emb,
                           float* __restrict__ embT) {
  int t = blockIdx.x >> 1, half = blockIdx.x & 1;
  for (int i = 0; i < 64; ++i) {
    int idx = half * 16384 + i * 256 + threadIdx.x;   // idx = k*64 + b
    int k = idx >> 6, b = idx & 63;
    int cap = captions[b * NT + t];
    embT[(size_t)t * (NE * NB) + idx] = emb[(size_t)cap * NE + k];
  }
}

// ---------------- att1 = enc(12544x2048) @ Wea(2048x512) + bea ----------------
__global__ void gemm_att1(const float* __restrict__ A, const float* __restrict__ Bw,
                          const float* __restrict__ bea, float* __restrict__ C) {
  __shared__ float As[16][64];   // [k][m]
  __shared__ float Bs[16][64];   // [k][n]
  int tid = threadIdx.x;
  int tx = tid & 15, ty = tid >> 4;
  int m0 = blockIdx.x * 64, n0 = blockIdx.y * 64;
  float acc[4][4] = {};
  for (int k0 = 0; k0 < ENCD; k0 += 16) {
    __syncthreads();
    {
      int m = tid >> 2, kq = tid & 3;
      const float4 a4 = *(const float4*)&A[(size_t)(m0 + m) * ENCD + k0 + kq * 4];
      As[kq * 4 + 0][m] = a4.x; As[kq * 4 + 1][m] = a4.y;
      As[kq * 4 + 2][m] = a4.z; As[kq * 4 + 3][m] = a4.w;
      for (int i = 0; i < 4; ++i) {
        int e = tid + i * 256; int k = e >> 6, n = e & 63;
        Bs[k][n] = Bw[(size_t)(k0 + k) * ATTD + n0 + n];
      }
    }
    __syncthreads();
#pragma unroll
    for (int kk = 0; kk < 16; ++kk) {
      float4 av = *(const float4*)&As[kk][ty * 4];
      float4 bv = *(const float4*)&Bs[kk][tx * 4];
      float a[4] = {av.x, av.y, av.z, av.w};
      float b[4] = {bv.x, bv.y, bv.z, bv.w};
#pragma unroll
      for (int i = 0; i < 4; ++i)
#pragma unroll
        for (int j = 0; j < 4; ++j) acc[i][j] += a[i] * b[j];
    }
  }
  for (int i = 0; i < 4; ++i)
    for (int j = 0; j < 4; ++j) {
      int m = m0 + ty * 4 + i, n = n0 + tx * 4 + j;
      C[(size_t)m * ATTD + n] = acc[i][j] + bea[n];
    }
}

// ---- colgemm: out[b][j] = sum_k xT[k*64+b] * W[k*J+j] + bias[j]
// lanes = j (coalesced weight rows), 16 b's per wave in accumulators,
// xT read at wave-uniform addresses (s_load bursts).
// writes outN[b*J+j] and/or transposed outT[j*64+b] (+ optional copy outT2).
__global__ void colgemm_kernel(const float* __restrict__ xT, int K,
                               const float* __restrict__ W, int J,
                               const float* __restrict__ bias,
                               float* __restrict__ outT, float* __restrict__ outT2,
                               float* __restrict__ outN) {
  int tid = threadIdx.x, lane = tid & 63, wid = tid >> 6;
  int j = blockIdx.x * 64 + lane;
  int b0 = __builtin_amdgcn_readfirstlane(wid * 16);
  float acc[16] = {};
#pragma unroll 4
  for (int k = 0; k < K; ++k) {
    float wv = W[(size_t)k * J + j];
    const float* xr = xT + k * 64 + b0;
#pragma unroll
    for (int i = 0; i < 16; ++i) acc[i] += xr[i] * wv;
  }
  float bv = bias ? bias[j] : 0.f;
#pragma unroll
  for (int i = 0; i < 16; ++i) {
    float o = acc[i] + bv;
    int b = b0 + i;
    if (outN) outN[(size_t)b * J + j] = o;
    if (outT) outT[(size_t)j * 64 + b] = o;
    if (outT2) outT2[(size_t)j * 64 + b] = o;
  }
}

// ---------------- e[b,p] = relu(att1[b,p,:]+att2[b,:]) . Wfa + bfa ----------------
__global__ void escore_kernel(const float* __restrict__ att1, const float* __restrict__ att2,
                              const float* __restrict__ Wfa, const float* __restrict__ bfa,
                              float* __restrict__ e) {
  int wid = threadIdx.x >> 6, lane = threadIdx.x & 63;
  int idx = blockIdx.x * 4 + wid;          // = b*196 + p
  int b = idx / NP;
  const float* arow = att1 + (size_t)idx * ATTD;
  const float* a2 = att2 + (size_t)b * ATTD;
  float acc = 0.f;
#pragma unroll
  for (int i = 0; i < 8; ++i) {
    int a = lane + i * 64;
    float v = arow[a] + a2[a];
    v = fmaxf(v, 0.f);
    acc += v * Wfa[a];
  }
  for (int off = 32; off; off >>= 1) acc += __shfl_xor(acc, off, 64);
  if (lane == 0) e[idx] = acc + bfa[0];
}

// ---------------- softmax over P then aweT[d*64+b] = sum_p alpha*enc ----------------
__global__ void smax_awe_kernel(const float* __restrict__ e, const float* __restrict__ enc,
                                float* __restrict__ aweT) {
  int b = blockIdx.x >> 3, dq = blockIdx.x & 7;
  int tid = threadIdx.x;
  __shared__ float sm[256];
  __shared__ float alpha[NP];
  float v = (tid < NP) ? e[b * NP + tid] : -1e30f;
  sm[tid] = v; __syncthreads();
  for (int s = 128; s; s >>= 1) { if (tid < s) sm[tid] = fmaxf(sm[tid], sm[tid + s]); __syncthreads(); }
  float m = sm[0]; __syncthreads();
  float ex = (tid < NP) ? expf(v - m) : 0.f;
  sm[tid] = ex; __syncthreads();
  for (int s = 128; s; s >>= 1) { if (tid < s) sm[tid] += sm[tid + s]; __syncthreads(); }
  float ssum = sm[0]; __syncthreads();
  if (tid < NP) alpha[tid] = ex / ssum;
  __syncthreads();
  int d = dq * 256 + tid;
  const float* base = enc + (size_t)b * NP * ENCD + d;
  float acc = 0.f;
  for (int p = 0; p < NP; ++p) acc += alpha[p] * base[(size_t)p * ENCD];
  aweT[d * NB + b] = acc;
}

// ---------------- fused LSTM gates + cell (wave per j0 in [0,512)) ----------------
__global__ void lstm_fused(const float* __restrict__ xT1, int K1,
                           const float* __restrict__ xT2, int K2,
                           const float* __restrict__ hT,
                           const float* __restrict__ W_ih, int ld_ih,
                           const float* __restrict__ W_hh,
                           const float* __restrict__ b_ih, const float* __restrict__ b_hh,
                           const float* __restrict__ cT_in,
                           float* __restrict__ hT_out, float* __restrict__ cT_out) {
  __shared__ float xs[4096];
  int tid = threadIdx.x, lane = tid & 63, wid = tid >> 6;
  int j0 = __builtin_amdgcn_readfirstlane(blockIdx.x * 4 + wid);   // [0,512)
  float ai = 0.f, af = 0.f, ag = 0.f, ao = 0.f;

  auto seg = [&](const float* __restrict__ src, int Ks, const float* __restrict__ Wb,
                 int ld, int c0) {
    const float* ri = Wb + (size_t)j0 * ld + c0;
    const float* rf = Wb + (size_t)(j0 + 512) * ld + c0;
    const float* rg = Wb + (size_t)(j0 + 1024) * ld + c0;
    const float* ro = Wb + (size_t)(j0 + 1536) * ld + c0;
    for (int k0 = 0; k0 < Ks; k0 += 64) {
      __syncthreads();
      for (int i = 0; i < 16; ++i) xs[i * 256 + tid] = src[k0 * 64 + i * 256 + tid];
      __syncthreads();
#pragma unroll 8
      for (int kk = 0; kk < 64; ++kk) {
        float xv = xs[kk * 64 + lane];
        int c = k0 + kk;
        ai += xv * ri[c]; af += xv * rf[c]; ag += xv * rg[c]; ao += xv * ro[c];
      }
    }
  };

  seg(xT1, K1, W_ih, ld_ih, 0);
  if (xT2) seg(xT2, K2, W_ih, ld_ih, K1);
  seg(hT, HIDD, W_hh, HIDD, 0);

  ai += b_ih[j0] + b_hh[j0];
  af += b_ih[j0 + 512] + b_hh[j0 + 512];
  ag += b_ih[j0 + 1024] + b_hh[j0 + 1024];
  ao += b_ih[j0 + 1536] + b_hh[j0 + 1536];
  float c_old = cT_in[j0 * 64 + lane];
  float si = 1.f / (1.f + expf(-ai));
  float sf = 1.f / (1.f + expf(-af));
  float so = 1.f / (1.f + expf(-ao));
  float cn = sf * c_old + si * tanhf(ag);
  float hn = so * tanhf(cn);
  hT_out[j0 * 64 + lane] = hn;
  cT_out[j0 * 64 + lane] = cn;
}

// ---------------- pred[b, t, v] = h1 . Wfc[:,v] + bfc[v] ----------------
__global__ void pred_kernel(const float* __restrict__ h1T, const float* __restrict__ Wfc,
                            const float* __restrict__ bfc, float* __restrict__ out, int t) {
  int tid = threadIdx.x, lane = tid & 63, wid = tid >> 6;
  int gw = blockIdx.x * 4 + wid;          // 0..999
  int vt = gw % 500, bh = gw / 500;       // 500 v-tiles x 2 b-halves
  int v = vt * 64 + lane;
  int b0 = __builtin_amdgcn_readfirstlane(bh * 32);
  float acc[32] = {};
  for (int h = 0; h < HIDD; ++h) {
    float w = Wfc[(size_t)h * NV + v];
    const float* hrow = h1T + h * 64 + b0;
#pragma unroll
    for (int i = 0; i < 32; ++i) acc[i] += hrow[i] * w;
  }
  float bv = bfc[v];
#pragma unroll
  for (int i = 0; i < 32; ++i)
    out[((size_t)(b0 + i) * NT + t) * NV + v] = acc[i] + bv;
}

extern "C" void kernel_launch(void* const* d_in, const int* in_sizes, int n_in,
                              void* d_out, int out_size, void* d_ws, size_t ws_size,
                              hipStream_t stream) {
  const float* enc   = (const float*)d_in[0];
  const int*   caps  = (const int*)d_in[1];
  const float* emb   = (const float*)d_in[3];
  const float* Wea   = (const float*)d_in[4];
  const float* bea   = (const float*)d_in[5];
  const float* Wda   = (const float*)d_in[6];
  const float* bda   = (const float*)d_in[7];
  const float* Wfa   = (const float*)d_in[8];
  const float* bfa   = (const float*)d_in[9];
  const float* W_ih0 = (const float*)d_in[10];
  const float* W_hh0 = (const float*)d_in[11];
  const float* b_ih0 = (const float*)d_in[12];
  const float* b_hh0 = (const float*)d_in[13];
  const float* W_ih1 = (const float*)d_in[14];
  const float* W_hh1 = (const float*)d_in[15];
  const float* b_ih1 = (const float*)d_in[16];
  const float* b_hh1 = (const float*)d_in[17];
  const float* Wfc   = (const float*)d_in[18];
  const float* bfc   = (const float*)d_in[19];
  const float* Wih   = (const float*)d_in[20];
  const float* bih   = (const float*)d_in[21];
  const float* Wic   = (const float*)d_in[22];
  const float* bic   = (const float*)d_in[23];
  float* out = (float*)d_out;

  float* w = (float*)d_ws;
  float* att1 = w;  w += (size_t)NB * NP * ATTD;   // 6,422,528
  float* meT  = w;  w += ENCD * NB;                // 131,072
  float* embT = w;  w += NT * NE * NB;             // 655,360
  float* aweT = w;  w += ENCD * NB;                // 131,072
  float* att2 = w;  w += NB * ATTD;                // 32,768
  float* ebuf = w;  w += NB * NP;                  // 12,544
  float* h0T[2] = { w, w + 32768 };  w += 65536;
  float* c0T[2] = { w, w + 32768 };  w += 65536;
  float* h1T[2] = { w, w + 32768 };  w += 65536;
  float* c1T[2] = { w, w + 32768 };  w += 65536;

  // ---- precompute ----
  mean_kernel<<<512, 256, 0, stream>>>(enc, meT);
  emb_kernel<<<NT * 2, 256, 0, stream>>>(caps, emb, embT);
  gemm_att1<<<dim3(NP * NB / 64, ATTD / 64), 256, 0, stream>>>(enc, Wea, bea, att1);
  // h0 = meanenc @ Wih + bih (copied to both layers); same for c
  colgemm_kernel<<<HIDD / 64, 256, 0, stream>>>(meT, ENCD, Wih, HIDD, bih,
                                                h0T[0], h1T[0], nullptr);
  colgemm_kernel<<<HIDD / 64, 256, 0, stream>>>(meT, ENCD, Wic, HIDD, bic,
                                                c0T[0], c1T[0], nullptr);

  int cur = 0;
  for (int t = 0; t < NT; ++t) {
    int nxt = cur ^ 1;
    // att2 = h1 @ Wda + bda  (normal layout [b][a])
    colgemm_kernel<<<ATTD / 64, 256, 0, stream>>>(h1T[cur], HIDD, Wda, ATTD, bda,
                                                  nullptr, nullptr, att2);
    escore_kernel<<<NB * NP / 4, 256, 0, stream>>>(att1, att2, Wfa, bfa, ebuf);
    smax_awe_kernel<<<512, 256, 0, stream>>>(ebuf, enc, aweT);
    lstm_fused<<<128, 256, 0, stream>>>(embT + (size_t)t * NE * NB, NE, aweT, ENCD,
                                        h0T[cur], W_ih0, NE + ENCD, W_hh0,
                                        b_ih0, b_hh0, c0T[cur], h0T[nxt], c0T[nxt]);
    lstm_fused<<<128, 256, 0, stream>>>(h0T[nxt], HIDD, nullptr, 0,
                                        h1T[cur], W_ih1, HIDD, W_hh1,
                                        b_ih1, b_hh1, c1T[cur], h1T[nxt], c1T[nxt]);
    pred_kernel<<<250, 256, 0, stream>>>(h1T[nxt], Wfc, bfc, out, t);
    cur = nxt;
  }
}

// Round 3
// 3322.056 us; speedup vs baseline: 3.4620x; 3.0870x over previous
//
#include <hip/hip_runtime.h>

#define ENCD 2048
#define ATTD 512
#define HIDD 512
#define NB 64
#define NP 196
#define NT 20
#define NV 32000
#define NE 512

using s8v = __attribute__((ext_vector_type(8))) short;   // 8 bf16 (4 VGPRs)
using f4v = __attribute__((ext_vector_type(4))) float;   // 4 f32 acc
#define MFMA_B16 __builtin_amdgcn_mfma_f32_16x16x32_bf16

__device__ inline short f2b(float f) {
  union { float f; unsigned u; } v; v.f = f;
  unsigned r = v.u + 0x7fff + ((v.u >> 16) & 1);
  return (short)(r >> 16);
}
__device__ inline float b2f(short s) {
  union { unsigned u; float f; } v; v.u = ((unsigned)(unsigned short)s) << 16;
  return v.f;
}

// ---------------- f32 -> bf16 bulk convert (float4 / short4) ----------------
__global__ void conv_bf16(const float* __restrict__ src, short* __restrict__ dst, int n4) {
  int i = blockIdx.x * 256 + threadIdx.x;
  if (i >= n4) return;
  float4 v = ((const float4*)src)[i];
  short4 o; o.x = f2b(v.x); o.y = f2b(v.y); o.z = f2b(v.z); o.w = f2b(v.w);
  ((short4*)dst)[i] = o;
}

// ---------------- mean over P: meT[k*64+b] = mean_p enc[b,p,k] (f32 exact) ----------------
__global__ void mean_kernel(const float* __restrict__ enc, float* __restrict__ meT) {
  int b = blockIdx.x >> 3, kq = blockIdx.x & 7;
  int k = kq * 256 + threadIdx.x;
  const float* base = enc + (size_t)b * NP * ENCD + k;
  float acc = 0.f;
  for (int p = 0; p < NP; ++p) acc += base[(size_t)p * ENCD];
  meT[k * NB + b] = acc * (1.f / NP);
}

// ---------------- embedding gather -> bf16 row-major embB[t][b][k] ----------------
__global__ void emb_b16(const int* __restrict__ caps, const float* __restrict__ emb,
                        short* __restrict__ embB) {
  int t = blockIdx.x / NB, b = blockIdx.x % NB;
  int cap = caps[b * NT + t];
  int k = threadIdx.x;
  for (int r = 0; r < 2; ++r, k += 256)
    embB[((size_t)t * NB + b) * NE + k] = f2b(emb[(size_t)cap * NE + k]);
}

// ---- swizzle builder: B[k][n] f32 row-major (ld = N) -> MFMA b-frag layout
// dst[(k0/32)*(N/16)+nt][lane][i] = B[k0+(lane>>4)*8+i][nt*16+(lane&15)]
__global__ void swz_rm(const float* __restrict__ B, int N, short* __restrict__ dst) {
  __shared__ short lt[256 * 32];          // [n within chunk][k]
  int tid = threadIdx.x;
  int k0 = blockIdx.x * 32, n0 = blockIdx.y * 256;
  for (int k = 0; k < 32; ++k)
    lt[tid * 32 + k] = f2b(B[(size_t)(k0 + k) * N + n0 + tid]);
  __syncthreads();
  int NT16 = N >> 4;
  for (int r = 0; r < 4; ++r) {
    int idx = r * 256 + tid;
    int lane = idx & 63, ntl = idx >> 6;
    int srcn = ntl * 16 + (lane & 15), srck = (lane >> 4) * 8;
    short* o = dst + ((size_t)blockIdx.x * NT16 + (n0 >> 4) + ntl) * 512 + lane * 8;
    for (int i = 0; i < 8; ++i) o[i] = lt[srcn * 32 + srck + i];
  }
}

// ---- LSTM combined weight swizzle: B[k][n] = (k<Kih ? W_ih[n][k] : W_hh[n][k-Kih]), N=2048
__global__ void swz_lstm(const float* __restrict__ Wih, int Kih, const float* __restrict__ Whh,
                         short* __restrict__ dst) {
  int tid = threadIdx.x, lane = tid & 63;
  int ct = blockIdx.y * 4 + (tid >> 6);         // column tile in [0,128)
  int n = ct * 16 + (lane & 15);
  int k = blockIdx.x * 32 + ((lane >> 4) << 3);
  short* o = dst + ((size_t)blockIdx.x * 128 + ct) * 512 + lane * 8;
  for (int i = 0; i < 8; ++i) {
    int kk = k + i;
    float f = (kk < Kih) ? Wih[(size_t)n * Kih + kk] : Whh[(size_t)n * 512 + (kk - Kih)];
    o[i] = f2b(f);
  }
}

__global__ void bias_sum(const float* __restrict__ a, const float* __restrict__ b,
                         float* __restrict__ o, int n) {
  int i = blockIdx.x * 256 + threadIdx.x;
  if (i < n) o[i] = a[i] + b[i];
}

// ---------------- att1 = encB(12544x2048) @ WeaS + bea -> f32 [12544][512] ----------------
// wave computes 64x64 (4 m-tiles x 4 n-tiles)
__global__ void att1_mfma(const short* __restrict__ A, const short* __restrict__ Bs,
                          const float* __restrict__ bias, float* __restrict__ C) {
  int lane = threadIdx.x & 63;
  int m0 = blockIdx.x * 64, n0t = blockIdx.y * 4;
  int mrow = lane & 15, kq = lane >> 4;
  f4v acc[4][4] = {};
  const short* aBase = A + (size_t)(m0 + mrow) * 2048 + kq * 8;
  const short* bBase = Bs + lane * 8;
#pragma unroll 2
  for (int ks = 0; ks < 64; ++ks) {
    s8v a[4], b[4];
    for (int mi = 0; mi < 4; ++mi) a[mi] = *(const s8v*)(aBase + mi * 16 * 2048 + ks * 32);
    for (int ni = 0; ni < 4; ++ni) b[ni] = *(const s8v*)(bBase + ((size_t)ks * 32 + n0t + ni) * 512);
    for (int mi = 0; mi < 4; ++mi)
      for (int ni = 0; ni < 4; ++ni)
        acc[mi][ni] = MFMA_B16(a[mi], b[ni], acc[mi][ni], 0, 0, 0);
  }
  for (int mi = 0; mi < 4; ++mi)
    for (int ni = 0; ni < 4; ++ni) {
      int col = n0t * 16 + ni * 16 + mrow;
      int rbase = m0 + mi * 16 + kq * 4;
      float bv = bias[col];
      for (int r = 0; r < 4; ++r) C[(size_t)(rbase + r) * 512 + col] = acc[mi][ni][r] + bv;
    }
}

// ---------------- fused LSTM: gates MFMA + cell epilogue ----------------
// A = [A1 | A2 | A3] bf16 row-major segments; wave = (m-tile, j-tile), 4 gate n-tiles
__global__ void lstm_mfma(const short* __restrict__ A1, int K1,
                          const short* __restrict__ A2, int K2,
                          const short* __restrict__ A3, int K3,
                          const short* __restrict__ Bs, const float* __restrict__ bias,
                          float* __restrict__ c_st, short* __restrict__ h_out) {
  int lane = threadIdx.x & 63;
  int mi = blockIdx.x, jt = blockIdx.y;
  int mrow = lane & 15, kq = lane >> 4;
  int m = mi * 16 + mrow;
  f4v acc[4] = {};
  const short* bBase = Bs + lane * 8;
  int Ktot = K1 + K2 + K3;
  for (int k0 = 0; k0 < Ktot; k0 += 32) {
    const short* ap; int kl;
    if (k0 < K1)            { ap = A1 + (size_t)m * K1; kl = k0; }
    else if (k0 < K1 + K2)  { ap = A2 + (size_t)m * K2; kl = k0 - K1; }
    else                    { ap = A3 + (size_t)m * K3; kl = k0 - K1 - K2; }
    s8v a = *(const s8v*)(ap + kl + kq * 8);
    int ksi = k0 >> 5;
#pragma unroll
    for (int g = 0; g < 4; ++g) {
      s8v b = *(const s8v*)(bBase + ((size_t)ksi * 128 + g * 32 + jt) * 512);
      acc[g] = MFMA_B16(a, b, acc[g], 0, 0, 0);
    }
  }
  int j = jt * 16 + mrow;
  float bi = bias[j], bf = bias[512 + j], bg = bias[1024 + j], bo = bias[1536 + j];
  for (int r = 0; r < 4; ++r) {
    int b = mi * 16 + kq * 4 + r;
    size_t idx = (size_t)b * 512 + j;
    float ii = acc[0][r] + bi, ff = acc[1][r] + bf, gg = acc[2][r] + bg, oo = acc[3][r] + bo;
    float c_old = c_st[idx];
    float si = 1.f / (1.f + expf(-ii));
    float sf = 1.f / (1.f + expf(-ff));
    float so = 1.f / (1.f + expf(-oo));
    float cn = sf * c_old + si * tanhf(gg);
    c_st[idx] = cn;
    h_out[idx] = f2b(so * tanhf(cn));
  }
}

// ---------------- att2 = h1 @ WdaS + bda -> f32 [64][512] ----------------
__global__ void att2_mfma(const short* __restrict__ A, const short* __restrict__ Bs,
                          const float* __restrict__ bias, float* __restrict__ C) {
  int lane = threadIdx.x & 63;
  int mi = blockIdx.x, nt = blockIdx.y;
  int mrow = lane & 15, kq = lane >> 4;
  f4v acc = {};
  const short* aBase = A + (size_t)(mi * 16 + mrow) * 512 + kq * 8;
  const short* bBase = Bs + lane * 8;
#pragma unroll
  for (int ks = 0; ks < 16; ++ks) {
    s8v a = *(const s8v*)(aBase + ks * 32);
    s8v b = *(const s8v*)(bBase + ((size_t)ks * 32 + nt) * 512);
    acc = MFMA_B16(a, b, acc, 0, 0, 0);
  }
  int col = nt * 16 + mrow;
  float bv = bias[col];
  for (int r = 0; r < 4; ++r) C[(size_t)(mi * 16 + kq * 4 + r) * 512 + col] = acc[r] + bv;
}

// ---------------- pred = h1 @ WfcS + bfc -> out[b][t][v] ----------------
__global__ void pred_mfma(const short* __restrict__ A, const short* __restrict__ Bs,
                          const float* __restrict__ bias, float* __restrict__ out, int t) {
  int lane = threadIdx.x & 63;
  int n0t = blockIdx.x * 4;
  int mrow = lane & 15, kq = lane >> 4;
  f4v acc[4][4] = {};
  const short* aBase = A + (size_t)mrow * 512 + kq * 8;
  const short* bBase = Bs + lane * 8;
#pragma unroll 2
  for (int ks = 0; ks < 16; ++ks) {
    s8v a[4], b[4];
    for (int mi = 0; mi < 4; ++mi) a[mi] = *(const s8v*)(aBase + mi * 16 * 512 + ks * 32);
    for (int ni = 0; ni < 4; ++ni) b[ni] = *(const s8v*)(bBase + ((size_t)ks * 2000 + n0t + ni) * 512);
    for (int mi = 0; mi < 4; ++mi)
      for (int ni = 0; ni < 4; ++ni)
        acc[mi][ni] = MFMA_B16(a[mi], b[ni], acc[mi][ni], 0, 0, 0);
  }
  for (int mi = 0; mi < 4; ++mi)
    for (int ni = 0; ni < 4; ++ni) {
      int v = n0t * 16 + ni * 16 + mrow;
      float bv = bias[v];
      for (int r = 0; r < 4; ++r) {
        int b = mi * 16 + kq * 4 + r;
        out[((size_t)b * NT + t) * NV + v] = acc[mi][ni][r] + bv;
      }
    }
}

// ---- init: h/c from meanpooled enc (f32 colgemm, row-major outputs) ----
__global__ void colgemm_init(const float* __restrict__ xT, int K,
                             const float* __restrict__ W, int J,
                             const float* __restrict__ bias,
                             short* __restrict__ hB0, short* __restrict__ hB1,
                             float* __restrict__ cF0, float* __restrict__ cF1) {
  int tid = threadIdx.x, lane = tid & 63, wid = tid >> 6;
  int j = blockIdx.x * 64 + lane;
  int b0 = __builtin_amdgcn_readfirstlane(wid * 16);
  float acc[16] = {};
#pragma unroll 4
  for (int k = 0; k < K; ++k) {
    float wv = W[(size_t)k * J + j];
    const float* xr = xT + k * 64 + b0;
#pragma unroll
    for (int i = 0; i < 16; ++i) acc[i] += xr[i] * wv;
  }
  float bv = bias[j];
#pragma unroll
  for (int i = 0; i < 16; ++i) {
    float o = acc[i] + bv;
    size_t idx = (size_t)(b0 + i) * J + j;
    if (hB0) { short s = f2b(o); hB0[idx] = s; hB1[idx] = s; }
    if (cF0) { cF0[idx] = o; cF1[idx] = o; }
  }
}

// ---------------- e[b,p] = relu(att1[b,p,:]+att2[b,:]) . Wfa + bfa ----------------
__global__ void escore_kernel(const float* __restrict__ att1, const float* __restrict__ att2,
                              const float* __restrict__ Wfa, const float* __restrict__ bfa,
                              float* __restrict__ e) {
  int wid = threadIdx.x >> 6, lane = threadIdx.x & 63;
  int idx = blockIdx.x * 4 + wid;
  int b = idx / NP;
  const float* arow = att1 + (size_t)idx * ATTD;
  const float* a2 = att2 + (size_t)b * ATTD;
  float acc = 0.f;
#pragma unroll
  for (int i = 0; i < 8; ++i) {
    int a = lane + i * 64;
    float v = arow[a] + a2[a];
    v = fmaxf(v, 0.f);
    acc += v * Wfa[a];
  }
  for (int off = 32; off; off >>= 1) acc += __shfl_xor(acc, off, 64);
  if (lane == 0) e[idx] = acc + bfa[0];
}

// ------- softmax over P then aweB[b][d] = bf16( sum_p alpha * encB[b,p,d] ) -------
__global__ void smax_awe_kernel(const float* __restrict__ e, const short* __restrict__ encB,
                                short* __restrict__ aweB) {
  int b = blockIdx.x >> 3, dq = blockIdx.x & 7;
  int tid = threadIdx.x;
  __shared__ float sm[256];
  __shared__ float alpha[NP];
  float v = (tid < NP) ? e[b * NP + tid] : -1e30f;
  sm[tid] = v; __syncthreads();
  for (int s = 128; s; s >>= 1) { if (tid < s) sm[tid] = fmaxf(sm[tid], sm[tid + s]); __syncthreads(); }
  float m = sm[0]; __syncthreads();
  float ex = (tid < NP) ? expf(v - m) : 0.f;
  sm[tid] = ex; __syncthreads();
  for (int s = 128; s; s >>= 1) { if (tid < s) sm[tid] += sm[tid + s]; __syncthreads(); }
  float ssum = sm[0]; __syncthreads();
  if (tid < NP) alpha[tid] = ex / ssum;
  __syncthreads();
  int d = dq * 256 + tid;
  const short* base = encB + (size_t)b * NP * ENCD + d;
  float acc = 0.f;
#pragma unroll 4
  for (int p = 0; p < NP; ++p) acc += alpha[p] * b2f(base[(size_t)p * ENCD]);
  aweB[(size_t)b * ENCD + d] = f2b(acc);
}

extern "C" void kernel_launch(void* const* d_in, const int* in_sizes, int n_in,
                              void* d_out, int out_size, void* d_ws, size_t ws_size,
                              hipStream_t stream) {
  const float* enc   = (const float*)d_in[0];
  const int*   caps  = (const int*)d_in[1];
  const float* emb   = (const float*)d_in[3];
  const float* Wea   = (const float*)d_in[4];
  const float* bea   = (const float*)d_in[5];
  const float* Wda   = (const float*)d_in[6];
  const float* bda   = (const float*)d_in[7];
  const float* Wfa   = (const float*)d_in[8];
  const float* bfa   = (const float*)d_in[9];
  const float* W_ih0 = (const float*)d_in[10];
  const float* W_hh0 = (const float*)d_in[11];
  const float* b_ih0 = (const float*)d_in[12];
  const float* b_hh0 = (const float*)d_in[13];
  const float* W_ih1 = (const float*)d_in[14];
  const float* W_hh1 = (const float*)d_in[15];
  const float* b_ih1 = (const float*)d_in[16];
  const float* b_hh1 = (const float*)d_in[17];
  const float* Wfc   = (const float*)d_in[18];
  const float* bfc   = (const float*)d_in[19];
  const float* Wih   = (const float*)d_in[20];
  const float* bih   = (const float*)d_in[21];
  const float* Wic   = (const float*)d_in[22];
  const float* bic   = (const float*)d_in[23];
  float* out = (float*)d_out;

  char* cw = (char*)d_ws;
  auto alloc = [&](size_t bytes) { char* p = cw; cw += (bytes + 255) & ~(size_t)255; return p; };
  short* encB = (short*)alloc((size_t)12544 * 2048 * 2);
  float* att1 = (float*)alloc((size_t)12544 * 512 * 4);
  short* embB = (short*)alloc((size_t)NT * NB * NE * 2);
  short* WeaS = (short*)alloc((size_t)2048 * 512 * 2);
  short* WdaS = (short*)alloc((size_t)512 * 512 * 2);
  short* WfcS = (short*)alloc((size_t)512 * 32000 * 2);
  short* Wl0S = (short*)alloc((size_t)3072 * 2048 * 2);
  short* Wl1S = (short*)alloc((size_t)1024 * 2048 * 2);
  float* meT  = (float*)alloc((size_t)2048 * 64 * 4);
  float* bsum0 = (float*)alloc(2048 * 4);
  float* bsum1 = (float*)alloc(2048 * 4);
  float* att2 = (float*)alloc((size_t)64 * 512 * 4);
  float* ebuf = (float*)alloc((size_t)64 * NP * 4);
  short* h0b[2] = { (short*)alloc(64 * 512 * 2), (short*)alloc(64 * 512 * 2) };
  short* h1b[2] = { (short*)alloc(64 * 512 * 2), (short*)alloc(64 * 512 * 2) };
  float* c0 = (float*)alloc(64 * 512 * 4);
  float* c1 = (float*)alloc(64 * 512 * 4);

  // ---- one-time precompute ----
  conv_bf16<<<(12544 * 2048 / 4 + 255) / 256, 256, 0, stream>>>(enc, encB, 12544 * 2048 / 4);
  mean_kernel<<<512, 256, 0, stream>>>(enc, meT);
  emb_b16<<<NT * NB, 256, 0, stream>>>(caps, emb, embB);
  swz_rm<<<dim3(64, 2), 256, 0, stream>>>(Wea, 512, WeaS);
  swz_rm<<<dim3(16, 2), 256, 0, stream>>>(Wda, 512, WdaS);
  swz_rm<<<dim3(16, 125), 256, 0, stream>>>(Wfc, 32000, WfcS);
  swz_lstm<<<dim3(96, 32), 256, 0, stream>>>(W_ih0, 2560, W_hh0, Wl0S);
  swz_lstm<<<dim3(32, 32), 256, 0, stream>>>(W_ih1, 512, W_hh1, Wl1S);
  bias_sum<<<8, 256, 0, stream>>>(b_ih0, b_hh0, bsum0, 2048);
  bias_sum<<<8, 256, 0, stream>>>(b_ih1, b_hh1, bsum1, 2048);
  att1_mfma<<<dim3(196, 8), 64, 0, stream>>>(encB, WeaS, bea, att1);
  colgemm_init<<<8, 256, 0, stream>>>(meT, ENCD, Wih, HIDD, bih, h0b[0], h1b[0], nullptr, nullptr);
  colgemm_init<<<8, 256, 0, stream>>>(meT, ENCD, Wic, HIDD, bic, nullptr, nullptr, c0, c1);

  short* aweB = (short*)alloc((size_t)64 * 2048 * 2);

  int cur = 0;
  for (int t = 0; t < NT; ++t) {
    int nxt = cur ^ 1;
    att2_mfma<<<dim3(4, 32), 64, 0, stream>>>(h1b[cur], WdaS, bda, att2);
    escore_kernel<<<NB * NP / 4, 256, 0, stream>>>(att1, att2, Wfa, bfa, ebuf);
    smax_awe_kernel<<<512, 256, 0, stream>>>(ebuf, encB, aweB);
    lstm_mfma<<<dim3(4, 32), 64, 0, stream>>>(embB + (size_t)t * NB * NE, NE,
                                              aweB, ENCD, h0b[cur], HIDD,
                                              Wl0S, bsum0, c0, h0b[nxt]);
    lstm_mfma<<<dim3(4, 32), 64, 0, stream>>>(h0b[nxt], HIDD, h1b[cur], HIDD,
                                              nullptr, 0,
                                              Wl1S, bsum1, c1, h1b[nxt]);
    pred_mfma<<<500, 64, 0, stream>>>(h1b[nxt], WfcS, bfc, out, t);
    cur = nxt;
  }
}

// Round 4
// 2732.066 us; speedup vs baseline: 4.2097x; 1.2160x over previous
//
#include <hip/hip_runtime.h>

#define ENCD 2048
#define ATTD 512
#define HIDD 512
#define NB 64
#define NP 196
#define NT 20
#define NV 32000
#define NE 512

using s8v = __attribute__((ext_vector_type(8))) short;   // 8 bf16 (4 VGPRs)
using f4v = __attribute__((ext_vector_type(4))) float;   // 4 f32 acc
#define MFMA_B16 __builtin_amdgcn_mfma_f32_16x16x32_bf16

__device__ inline short f2b(float f) {
  union { float f; unsigned u; } v; v.f = f;
  unsigned r = v.u + 0x7fff + ((v.u >> 16) & 1);
  return (short)(r >> 16);
}
__device__ inline float b2f(short s) {
  union { unsigned u; float f; } v; v.u = ((unsigned)(unsigned short)s) << 16;
  return v.f;
}

// ---------------- f32 -> bf16 bulk convert (float4 / short4) ----------------
__global__ void conv_bf16(const float* __restrict__ src, short* __restrict__ dst, int n4) {
  int i = blockIdx.x * 256 + threadIdx.x;
  if (i >= n4) return;
  float4 v = ((const float4*)src)[i];
  short4 o; o.x = f2b(v.x); o.y = f2b(v.y); o.z = f2b(v.z); o.w = f2b(v.w);
  ((short4*)dst)[i] = o;
}

// ------- mean over P -> bf16 row-major meB[b][k] = mean_p enc[b,p,k] -------
__global__ void mean_kernel(const float* __restrict__ enc, short* __restrict__ meB) {
  int b = blockIdx.x >> 3, kq = blockIdx.x & 7;
  int k = kq * 256 + threadIdx.x;
  const float* base = enc + (size_t)b * NP * ENCD + k;
  float acc = 0.f;
  for (int p = 0; p < NP; ++p) acc += base[(size_t)p * ENCD];
  meB[(size_t)b * ENCD + k] = f2b(acc * (1.f / NP));
}

// ---------------- embedding gather -> bf16 row-major embB[t][b][k] ----------------
__global__ void emb_b16(const int* __restrict__ caps, const float* __restrict__ emb,
                        short* __restrict__ embB) {
  int t = blockIdx.x / NB, b = blockIdx.x % NB;
  int cap = caps[b * NT + t];
  int k = threadIdx.x;
  for (int r = 0; r < 2; ++r, k += 256)
    embB[((size_t)t * NB + b) * NE + k] = f2b(emb[(size_t)cap * NE + k]);
}

// ---- swizzle builder: B[k][n] f32 row-major (ld = N) -> MFMA b-frag layout
// dst[(k0/32)*(N/16)+nt][lane][i] = B[k0+(lane>>4)*8+i][nt*16+(lane&15)]
__global__ void swz_rm(const float* __restrict__ B, int N, short* __restrict__ dst) {
  __shared__ short lt[256 * 32];          // [n within chunk][k]
  int tid = threadIdx.x;
  int k0 = blockIdx.x * 32, n0 = blockIdx.y * 256;
  for (int k = 0; k < 32; ++k)
    lt[tid * 32 + k] = f2b(B[(size_t)(k0 + k) * N + n0 + tid]);
  __syncthreads();
  int NT16 = N >> 4;
  for (int r = 0; r < 4; ++r) {
    int idx = r * 256 + tid;
    int lane = idx & 63, ntl = idx >> 6;
    int srcn = ntl * 16 + (lane & 15), srck = (lane >> 4) * 8;
    short* o = dst + ((size_t)blockIdx.x * NT16 + (n0 >> 4) + ntl) * 512 + lane * 8;
    for (int i = 0; i < 8; ++i) o[i] = lt[srcn * 32 + srck + i];
  }
}

// ---- LSTM combined weight swizzle: B[k][n] = (k<Kih ? W_ih[n][k] : W_hh[n][k-Kih]), N=2048
__global__ void swz_lstm(const float* __restrict__ Wih, int Kih, const float* __restrict__ Whh,
                         short* __restrict__ dst) {
  int tid = threadIdx.x, lane = tid & 63;
  int ct = blockIdx.y * 4 + (tid >> 6);         // column tile in [0,128)
  int n = ct * 16 + (lane & 15);
  int k = blockIdx.x * 32 + ((lane >> 4) << 3);
  short* o = dst + ((size_t)blockIdx.x * 128 + ct) * 512 + lane * 8;
  for (int i = 0; i < 8; ++i) {
    int kk = k + i;
    float f = (kk < Kih) ? Wih[(size_t)n * Kih + kk] : Whh[(size_t)n * 512 + (kk - Kih)];
    o[i] = f2b(f);
  }
}

__global__ void bias_sum(const float* __restrict__ a, const float* __restrict__ b,
                         float* __restrict__ o, int n) {
  int i = blockIdx.x * 256 + threadIdx.x;
  if (i < n) o[i] = a[i] + b[i];
}

// ---------------- att1 = encB(12544x2048) @ WeaS + bea -> f32 [12544][512] ----------------
// wave computes 64x64 (4 m-tiles x 4 n-tiles)
__global__ void att1_mfma(const short* __restrict__ A, const short* __restrict__ Bs,
                          const float* __restrict__ bias, float* __restrict__ C) {
  int lane = threadIdx.x & 63;
  int m0 = blockIdx.x * 64, n0t = blockIdx.y * 4;
  int mrow = lane & 15, kq = lane >> 4;
  f4v acc[4][4] = {};
  const short* aBase = A + (size_t)(m0 + mrow) * 2048 + kq * 8;
  const short* bBase = Bs + lane * 8;
#pragma unroll 2
  for (int ks = 0; ks < 64; ++ks) {
    s8v a[4], b[4];
    for (int mi = 0; mi < 4; ++mi) a[mi] = *(const s8v*)(aBase + mi * 16 * 2048 + ks * 32);
    for (int ni = 0; ni < 4; ++ni) b[ni] = *(const s8v*)(bBase + ((size_t)ks * 32 + n0t + ni) * 512);
    for (int mi = 0; mi < 4; ++mi)
      for (int ni = 0; ni < 4; ++ni)
        acc[mi][ni] = MFMA_B16(a[mi], b[ni], acc[mi][ni], 0, 0, 0);
  }
  for (int mi = 0; mi < 4; ++mi)
    for (int ni = 0; ni < 4; ++ni) {
      int col = n0t * 16 + ni * 16 + mrow;
      int rbase = m0 + mi * 16 + kq * 4;
      float bv = bias[col];
      for (int r = 0; r < 4; ++r) C[(size_t)(rbase + r) * 512 + col] = acc[mi][ni][r] + bv;
    }
}

// ---- init h/c via MFMA: h = meB @ WihS + bih (bf16 x2), c = meB @ WicS + bic (f32 x2)
__global__ void init_mfma(const short* __restrict__ A,
                          const short* __restrict__ BsH, const short* __restrict__ BsC,
                          const float* __restrict__ bih, const float* __restrict__ bic,
                          short* __restrict__ h0, short* __restrict__ h1,
                          float* __restrict__ c0v, float* __restrict__ c1v) {
  int lane = threadIdx.x & 63;
  int mi = blockIdx.x, jt0 = blockIdx.y;        // jt0 in [0,64)
  bool isC = jt0 >= 32;
  int jt = jt0 & 31;
  const short* Bs = isC ? BsC : BsH;
  int mrow = lane & 15, kq = lane >> 4;
  f4v acc = {};
  const short* aBase = A + (size_t)(mi * 16 + mrow) * 2048 + kq * 8;
  const short* bBase = Bs + lane * 8;
#pragma unroll 4
  for (int ks = 0; ks < 64; ++ks) {
    s8v a = *(const s8v*)(aBase + ks * 32);
    s8v b = *(const s8v*)(bBase + ((size_t)ks * 32 + jt) * 512);
    acc = MFMA_B16(a, b, acc, 0, 0, 0);
  }
  int j = jt * 16 + mrow;
  float bv = (isC ? bic : bih)[j];
  for (int r = 0; r < 4; ++r) {
    int b = mi * 16 + kq * 4 + r;
    size_t idx = (size_t)b * 512 + j;
    float o = acc[r] + bv;
    if (isC) { c0v[idx] = o; c1v[idx] = o; }
    else     { short s = f2b(o); h0[idx] = s; h1[idx] = s; }
  }
}

// ---------------- fused LSTM: gates MFMA + cell epilogue ----------------
// A = [A1 | A2 | A3] bf16 row-major segments; wave = (m-tile, j-tile), 4 gate n-tiles
__global__ void lstm_mfma(const short* __restrict__ A1, int K1,
                          const short* __restrict__ A2, int K2,
                          const short* __restrict__ A3, int K3,
                          const short* __restrict__ Bs, const float* __restrict__ bias,
                          float* __restrict__ c_st, short* __restrict__ h_out) {
  int lane = threadIdx.x & 63;
  int mi = blockIdx.x, jt = blockIdx.y;
  int mrow = lane & 15, kq = lane >> 4;
  int m = mi * 16 + mrow;
  f4v acc[4] = {};
  const short* bBase = Bs + lane * 8;
  int Ktot = K1 + K2 + K3;
  for (int k0 = 0; k0 < Ktot; k0 += 32) {
    const short* ap; int kl;
    if (k0 < K1)            { ap = A1 + (size_t)m * K1; kl = k0; }
    else if (k0 < K1 + K2)  { ap = A2 + (size_t)m * K2; kl = k0 - K1; }
    else                    { ap = A3 + (size_t)m * K3; kl = k0 - K1 - K2; }
    s8v a = *(const s8v*)(ap + kl + kq * 8);
    int ksi = k0 >> 5;
#pragma unroll
    for (int g = 0; g < 4; ++g) {
      s8v b = *(const s8v*)(bBase + ((size_t)ksi * 128 + g * 32 + jt) * 512);
      acc[g] = MFMA_B16(a, b, acc[g], 0, 0, 0);
    }
  }
  int j = jt * 16 + mrow;
  float bi = bias[j], bf = bias[512 + j], bg = bias[1024 + j], bo = bias[1536 + j];
  for (int r = 0; r < 4; ++r) {
    int b = mi * 16 + kq * 4 + r;
    size_t idx = (size_t)b * 512 + j;
    float ii = acc[0][r] + bi, ff = acc[1][r] + bf, gg = acc[2][r] + bg, oo = acc[3][r] + bo;
    float c_old = c_st[idx];
    float si = 1.f / (1.f + expf(-ii));
    float sf = 1.f / (1.f + expf(-ff));
    float so = 1.f / (1.f + expf(-oo));
    float cn = sf * c_old + si * tanhf(gg);
    c_st[idx] = cn;
    h_out[idx] = f2b(so * tanhf(cn));
  }
}

// ---------------- att2 = h1 @ WdaS + bda -> f32 [64][512] ----------------
__global__ void att2_mfma(const short* __restrict__ A, const short* __restrict__ Bs,
                          const float* __restrict__ bias, float* __restrict__ C) {
  int lane = threadIdx.x & 63;
  int mi = blockIdx.x, nt = blockIdx.y;
  int mrow = lane & 15, kq = lane >> 4;
  f4v acc = {};
  const short* aBase = A + (size_t)(mi * 16 + mrow) * 512 + kq * 8;
  const short* bBase = Bs + lane * 8;
#pragma unroll
  for (int ks = 0; ks < 16; ++ks) {
    s8v a = *(const s8v*)(aBase + ks * 32);
    s8v b = *(const s8v*)(bBase + ((size_t)ks * 32 + nt) * 512);
    acc = MFMA_B16(a, b, acc, 0, 0, 0);
  }
  int col = nt * 16 + mrow;
  float bv = bias[col];
  for (int r = 0; r < 4; ++r) C[(size_t)(mi * 16 + kq * 4 + r) * 512 + col] = acc[r] + bv;
}

// ---------------- pred = h1 @ WfcS + bfc -> out[b][t][v] ----------------
__global__ void pred_mfma(const short* __restrict__ A, const short* __restrict__ Bs,
                          const float* __restrict__ bias, float* __restrict__ out, int t) {
  int lane = threadIdx.x & 63;
  int n0t = blockIdx.x * 4;
  int mrow = lane & 15, kq = lane >> 4;
  f4v acc[4][4] = {};
  const short* aBase = A + (size_t)mrow * 512 + kq * 8;
  const short* bBase = Bs + lane * 8;
#pragma unroll 2
  for (int ks = 0; ks < 16; ++ks) {
    s8v a[4], b[4];
    for (int mi = 0; mi < 4; ++mi) a[mi] = *(const s8v*)(aBase + mi * 16 * 512 + ks * 32);
    for (int ni = 0; ni < 4; ++ni) b[ni] = *(const s8v*)(bBase + ((size_t)ks * 2000 + n0t + ni) * 512);
    for (int mi = 0; mi < 4; ++mi)
      for (int ni = 0; ni < 4; ++ni)
        acc[mi][ni] = MFMA_B16(a[mi], b[ni], acc[mi][ni], 0, 0, 0);
  }
  for (int mi = 0; mi < 4; ++mi)
    for (int ni = 0; ni < 4; ++ni) {
      int v = n0t * 16 + ni * 16 + mrow;
      float bv = bias[v];
      for (int r = 0; r < 4; ++r) {
        int b = mi * 16 + kq * 4 + r;
        out[((size_t)b * NT + t) * NV + v] = acc[mi][ni][r] + bv;
      }
    }
}

// ---------------- e[b,p] = relu(att1[b,p,:]+att2[b,:]) . Wfa + bfa ----------------
__global__ void escore_kernel(const float* __restrict__ att1, const float* __restrict__ att2,
                              const float* __restrict__ Wfa, const float* __restrict__ bfa,
                              float* __restrict__ e) {
  int wid = threadIdx.x >> 6, lane = threadIdx.x & 63;
  int idx = blockIdx.x * 4 + wid;
  int b = idx / NP;
  const float* arow = att1 + (size_t)idx * ATTD;
  const float* a2 = att2 + (size_t)b * ATTD;
  float acc = 0.f;
#pragma unroll
  for (int i = 0; i < 8; ++i) {
    int a = lane + i * 64;
    float v = arow[a] + a2[a];
    v = fmaxf(v, 0.f);
    acc += v * Wfa[a];
  }
  for (int off = 32; off; off >>= 1) acc += __shfl_xor(acc, off, 64);
  if (lane == 0) e[idx] = acc + bfa[0];
}

// ------- softmax over P then aweB[b][d] = bf16( sum_p alpha * encB[b,p,d] ) -------
__global__ void smax_awe_kernel(const float* __restrict__ e, const short* __restrict__ encB,
                                short* __restrict__ aweB) {
  int b = blockIdx.x >> 3, dq = blockIdx.x & 7;
  int tid = threadIdx.x;
  __shared__ float sm[256];
  __shared__ float alpha[NP];
  float v = (tid < NP) ? e[b * NP + tid] : -1e30f;
  sm[tid] = v; __syncthreads();
  for (int s = 128; s; s >>= 1) { if (tid < s) sm[tid] = fmaxf(sm[tid], sm[tid + s]); __syncthreads(); }
  float m = sm[0]; __syncthreads();
  float ex = (tid < NP) ? expf(v - m) : 0.f;
  sm[tid] = ex; __syncthreads();
  for (int s = 128; s; s >>= 1) { if (tid < s) sm[tid] += sm[tid + s]; __syncthreads(); }
  float ssum = sm[0]; __syncthreads();
  if (tid < NP) alpha[tid] = ex / ssum;
  __syncthreads();
  int d = dq * 256 + tid;
  const short* base = encB + (size_t)b * NP * ENCD + d;
  float acc = 0.f;
#pragma unroll 4
  for (int p = 0; p < NP; ++p) acc += alpha[p] * b2f(base[(size_t)p * ENCD]);
  aweB[(size_t)b * ENCD + d] = f2b(acc);
}

extern "C" void kernel_launch(void* const* d_in, const int* in_sizes, int n_in,
                              void* d_out, int out_size, void* d_ws, size_t ws_size,
                              hipStream_t stream) {
  const float* enc   = (const float*)d_in[0];
  const int*   caps  = (const int*)d_in[1];
  const float* emb   = (const float*)d_in[3];
  const float* Wea   = (const float*)d_in[4];
  const float* bea   = (const float*)d_in[5];
  const float* Wda   = (const float*)d_in[6];
  const float* bda   = (const float*)d_in[7];
  const float* Wfa   = (const float*)d_in[8];
  const float* bfa   = (const float*)d_in[9];
  const float* W_ih0 = (const float*)d_in[10];
  const float* W_hh0 = (const float*)d_in[11];
  const float* b_ih0 = (const float*)d_in[12];
  const float* b_hh0 = (const float*)d_in[13];
  const float* W_ih1 = (const float*)d_in[14];
  const float* W_hh1 = (const float*)d_in[15];
  const float* b_ih1 = (const float*)d_in[16];
  const float* b_hh1 = (const float*)d_in[17];
  const float* Wfc   = (const float*)d_in[18];
  const float* bfc   = (const float*)d_in[19];
  const float* Wih   = (const float*)d_in[20];
  const float* bih   = (const float*)d_in[21];
  const float* Wic   = (const float*)d_in[22];
  const float* bic   = (const float*)d_in[23];
  float* out = (float*)d_out;

  char* cw = (char*)d_ws;
  auto alloc = [&](size_t bytes) { char* p = cw; cw += (bytes + 255) & ~(size_t)255; return p; };
  short* encB = (short*)alloc((size_t)12544 * 2048 * 2);
  float* att1 = (float*)alloc((size_t)12544 * 512 * 4);
  short* embB = (short*)alloc((size_t)NT * NB * NE * 2);
  short* WeaS = (short*)alloc((size_t)2048 * 512 * 2);
  short* WdaS = (short*)alloc((size_t)512 * 512 * 2);
  short* WfcS = (short*)alloc((size_t)512 * 32000 * 2);
  short* Wl0S = (short*)alloc((size_t)3072 * 2048 * 2);
  short* Wl1S = (short*)alloc((size_t)1024 * 2048 * 2);
  short* WihS = (short*)alloc((size_t)2048 * 512 * 2);
  short* WicS = (short*)alloc((size_t)2048 * 512 * 2);
  short* meB  = (short*)alloc((size_t)64 * 2048 * 2);
  float* bsum0 = (float*)alloc(2048 * 4);
  float* bsum1 = (float*)alloc(2048 * 4);
  float* att2 = (float*)alloc((size_t)64 * 512 * 4);
  float* ebuf = (float*)alloc((size_t)64 * NP * 4);
  short* h0b[2] = { (short*)alloc(64 * 512 * 2), (short*)alloc(64 * 512 * 2) };
  short* h1b[2] = { (short*)alloc(64 * 512 * 2), (short*)alloc(64 * 512 * 2) };
  float* c0 = (float*)alloc(64 * 512 * 4);
  float* c1 = (float*)alloc(64 * 512 * 4);
  short* aweB = (short*)alloc((size_t)64 * 2048 * 2);

  // ---- one-time precompute ----
  conv_bf16<<<(12544 * 2048 / 4 + 255) / 256, 256, 0, stream>>>(enc, encB, 12544 * 2048 / 4);
  mean_kernel<<<512, 256, 0, stream>>>(enc, meB);
  emb_b16<<<NT * NB, 256, 0, stream>>>(caps, emb, embB);
  swz_rm<<<dim3(64, 2), 256, 0, stream>>>(Wea, 512, WeaS);
  swz_rm<<<dim3(16, 2), 256, 0, stream>>>(Wda, 512, WdaS);
  swz_rm<<<dim3(16, 125), 256, 0, stream>>>(Wfc, 32000, WfcS);
  swz_rm<<<dim3(64, 2), 256, 0, stream>>>(Wih, 512, WihS);
  swz_rm<<<dim3(64, 2), 256, 0, stream>>>(Wic, 512, WicS);
  swz_lstm<<<dim3(96, 32), 256, 0, stream>>>(W_ih0, 2560, W_hh0, Wl0S);
  swz_lstm<<<dim3(32, 32), 256, 0, stream>>>(W_ih1, 512, W_hh1, Wl1S);
  bias_sum<<<8, 256, 0, stream>>>(b_ih0, b_hh0, bsum0, 2048);
  bias_sum<<<8, 256, 0, stream>>>(b_ih1, b_hh1, bsum1, 2048);
  att1_mfma<<<dim3(196, 8), 64, 0, stream>>>(encB, WeaS, bea, att1);
  init_mfma<<<dim3(4, 64), 64, 0, stream>>>(meB, WihS, WicS, bih, bic,
                                            h0b[0], h1b[0], c0, c1);

  int cur = 0;
  for (int t = 0; t < NT; ++t) {
    int nxt = cur ^ 1;
    att2_mfma<<<dim3(4, 32), 64, 0, stream>>>(h1b[cur], WdaS, bda, att2);
    escore_kernel<<<NB * NP / 4, 256, 0, stream>>>(att1, att2, Wfa, bfa, ebuf);
    smax_awe_kernel<<<512, 256, 0, stream>>>(ebuf, encB, aweB);
    lstm_mfma<<<dim3(4, 32), 64, 0, stream>>>(embB + (size_t)t * NB * NE, NE,
                                              aweB, ENCD, h0b[cur], HIDD,
                                              Wl0S, bsum0, c0, h0b[nxt]);
    lstm_mfma<<<dim3(4, 32), 64, 0, stream>>>(h0b[nxt], HIDD, h1b[cur], HIDD,
                                              nullptr, 0,
                                              Wl1S, bsum1, c1, h1b[nxt]);
    pred_mfma<<<500, 64, 0, stream>>>(h1b[nxt], WfcS, bfc, out, t);
    cur = nxt;
  }
}